// Round 2
// baseline (568.678 us; speedup 1.0000x reference)
//
#include <hip/hip_runtime.h>
#include <hip/hip_bf16.h>

#define T_TOKENS 2048
#define H_DIM    2048
#define I_DIM    1408
#define E_NUM    8

typedef __bf16 bf16;
typedef __attribute__((ext_vector_type(4))) __bf16  bf16x4;
typedef __attribute__((ext_vector_type(8))) __bf16  bf16x8;
typedef __attribute__((ext_vector_type(4))) float   floatx4;

// ---------------- ws layout (bytes) ----------------
static const size_t OFF_COUNTS = 0;                                   // 32 B
static const size_t OFF_LISTS  = 256;                                 // E*T*4 = 64 KB
static const size_t OFF_WLISTS = OFF_LISTS + (size_t)T_TOKENS * E_NUM * 4;
static const size_t OFF_XB     = 131328;                              // [T][H] bf16 = 8 MB
static const size_t OFF_ACT    = OFF_XB + (size_t)T_TOKENS * H_DIM * 2;       // [2T][I] bf16 = 11.5 MB
static const size_t OFF_GUPK   = OFF_ACT + (size_t)2 * T_TOKENS * I_DIM * 2;  // packed gu = 23 MB
static const size_t OFF_DNPK   = OFF_GUPK + (size_t)E_NUM * 2 * I_DIM * (H_DIM / 8) * 4; // packed dn = 11.5 MB
// total ≈ 54.7 MB

// ---------------- pack int32 (values 0..15) -> nibbles, 8 per dword ----------------
// each thread: 16 int32 (64 B) -> uint2 (8 B). n2 = total_elems/16.
__global__ void pack_nib_kernel(const int* __restrict__ q, uint2* __restrict__ out, int n2)
{
    int i = blockIdx.x * blockDim.x + threadIdx.x;
    if (i >= n2) return;
    const int4* q4 = reinterpret_cast<const int4*>(q) + (size_t)i * 4;
    int4 a = q4[0], b = q4[1], c = q4[2], d = q4[3];
    unsigned d0 = (unsigned)(a.x & 15) | ((unsigned)(a.y & 15) << 4) |
                  ((unsigned)(a.z & 15) << 8) | ((unsigned)(a.w & 15) << 12) |
                  ((unsigned)(b.x & 15) << 16) | ((unsigned)(b.y & 15) << 20) |
                  ((unsigned)(b.z & 15) << 24) | ((unsigned)(b.w & 15) << 28);
    unsigned d1 = (unsigned)(c.x & 15) | ((unsigned)(c.y & 15) << 4) |
                  ((unsigned)(c.z & 15) << 8) | ((unsigned)(c.w & 15) << 12) |
                  ((unsigned)(d.x & 15) << 16) | ((unsigned)(d.y & 15) << 20) |
                  ((unsigned)(d.z & 15) << 24) | ((unsigned)(d.w & 15) << 28);
    out[i] = make_uint2(d0, d1);
}

// ---------------- x f32 -> bf16 ----------------
__global__ void xconv_kernel(const float* __restrict__ x, bf16* __restrict__ xb)
{
    int i = blockIdx.x * blockDim.x + threadIdx.x;   // one bf16x8 per thread
    const float4* x4 = reinterpret_cast<const float4*>(x) + (size_t)i * 2;
    float4 v0 = x4[0], v1 = x4[1];
    bf16x8 bv;
    bv[0] = (bf16)v0.x; bv[1] = (bf16)v0.y; bv[2] = (bf16)v0.z; bv[3] = (bf16)v0.w;
    bv[4] = (bf16)v1.x; bv[5] = (bf16)v1.y; bv[6] = (bf16)v1.z; bv[7] = (bf16)v1.w;
    *reinterpret_cast<bf16x8*>(xb + (size_t)i * 8) = bv;
}

// ---------------- routing ----------------
__global__ void router_kernel(const float* __restrict__ logits,
                              int* __restrict__ counts,
                              int* __restrict__ lists,
                              float* __restrict__ wlists)
{
    int t = blockIdx.x * blockDim.x + threadIdx.x;
    if (t >= T_TOKENS) return;
    const float* l = logits + (size_t)t * E_NUM;
    float v0 = -1e30f, v1 = -1e30f;
    int i0 = 0, i1 = 0;
    #pragma unroll
    for (int e = 0; e < E_NUM; ++e) {
        float v = l[e];
        if (v > v0) { v1 = v0; i1 = i0; v0 = v; i0 = e; }
        else if (v > v1) { v1 = v; i1 = e; }
    }
    float w0 = 1.f / (1.f + __expf(v1 - v0));
    float w1 = 1.f - w0;
    int p0 = atomicAdd(&counts[i0], 1);
    lists[i0 * T_TOKENS + p0] = t * 2 + 0;
    wlists[i0 * T_TOKENS + p0] = w0;
    int p1 = atomicAdd(&counts[i1], 1);
    lists[i1 * T_TOKENS + p1] = t * 2 + 1;
    wlists[i1 * T_TOKENS + p1] = w1;
}

// ---------------- GEMM1: x @ W_gate_up^T (nibble-packed), fused SwiGLU ----------------
__global__ __launch_bounds__(256) void gemm1_kernel(
    const bf16*     __restrict__ xb,
    const unsigned* __restrict__ qpk,   // [E][2I][H/8] nibbles
    const float*    __restrict__ sc,    // [E][2I][16]
    const int*      __restrict__ counts,
    const int*      __restrict__ lists,
    bf16*           __restrict__ act)   // [2T][I]
{
    const int e   = blockIdx.z;
    const int cnt = counts[e];
    const int m0  = blockIdx.y * 128;
    if (m0 >= cnt) return;
    const int n0 = blockIdx.x * 64;

    __shared__ __align__(16) bf16 Al[128 * 64];
    __shared__ __align__(16) bf16 Bl[128 * 64];
    __shared__ int meta[128];

    const int tid = threadIdx.x;
    if (tid < 128) {
        int m = m0 + tid;
        meta[tid] = lists[e * T_TOKENS + (m < cnt ? m : 0)];
    }
    __syncthreads();

    const int lane = tid & 63;
    const int wv = tid >> 6;
    const int wm = wv >> 1, wn = wv & 1;

    floatx4 acc[4][4];
    #pragma unroll
    for (int i = 0; i < 4; ++i)
        #pragma unroll
        for (int j = 0; j < 4; ++j)
            acc[i][j] = (floatx4){0.f, 0.f, 0.f, 0.f};

    // per-thread B row/granule (4 rows, same granule)
    const int kg   = tid & 7;       // 16B granule (8 values)
    const int rb   = tid >> 3;      // base row 0..31, +32 per j

    for (int k0 = 0; k0 < H_DIM; k0 += 64) {
        // ---- stage A: gathered bf16 rows, pure copy ----
        #pragma unroll
        for (int j = 0; j < 4; ++j) {
            int g = tid + 256 * j;          // granule id
            int row = g >> 3, cg = g & 7;
            int tok = meta[row] >> 1;
            bf16x8 v = *reinterpret_cast<const bf16x8*>(xb + (size_t)tok * H_DIM + k0 + cg * 8);
            *reinterpret_cast<bf16x8*>(&Al[g * 8]) = v;
        }
        // ---- stage B: nibble dequant, gate/up interleaved rows ----
        #pragma unroll
        for (int j = 0; j < 4; ++j) {
            int r = rb + 32 * j;
            int tt = r >> 4, within = r & 15;
            int grow = ((tt & 1) ? I_DIM : 0) + n0 + (tt >> 1) * 16 + within;
            size_t rbase = (size_t)(e * 2816 + grow);
            unsigned pd = qpk[rbase * 256 + (k0 >> 3) + kg];
            float s = sc[rbase * 16 + (k0 >> 7)];
            float m8s = -8.f * s;
            bf16x8 bv;
            #pragma unroll
            for (int jj = 0; jj < 8; ++jj)
                bv[jj] = (bf16)fmaf((float)((pd >> (4 * jj)) & 15u), s, m8s);
            *reinterpret_cast<bf16x8*>(&Bl[r * 64 + kg * 8]) = bv;
        }
        __syncthreads();
        #pragma unroll
        for (int ks = 0; ks < 2; ++ks) {
            const int kofs = ks * 32 + (lane >> 4) * 8;
            bf16x8 af[4], bfr[4];
            #pragma unroll
            for (int mt = 0; mt < 4; ++mt)
                af[mt] = *reinterpret_cast<const bf16x8*>(&Al[(wm * 64 + mt * 16 + (lane & 15)) * 64 + kofs]);
            #pragma unroll
            for (int nt = 0; nt < 4; ++nt)
                bfr[nt] = *reinterpret_cast<const bf16x8*>(&Bl[(wn * 64 + nt * 16 + (lane & 15)) * 64 + kofs]);
            #pragma unroll
            for (int mt = 0; mt < 4; ++mt)
                #pragma unroll
                for (int nt = 0; nt < 4; ++nt)
                    acc[mt][nt] = __builtin_amdgcn_mfma_f32_16x16x32_bf16(af[mt], bfr[nt], acc[mt][nt], 0, 0, 0);
        }
        __syncthreads();
    }

    // ---- epilogue: SwiGLU + scatter ----
    const int rbase = (lane >> 4) * 4;
    const int cn = lane & 15;
    #pragma unroll
    for (int mt = 0; mt < 4; ++mt) {
        #pragma unroll
        for (int j = 0; j < 2; ++j) {
            floatx4 g = acc[mt][2 * j];
            floatx4 u = acc[mt][2 * j + 1];
            int col = n0 + wn * 32 + j * 16 + cn;
            #pragma unroll
            for (int r = 0; r < 4; ++r) {
                int lrow = wm * 64 + mt * 16 + rbase + r;
                if (m0 + lrow < cnt) {
                    float gate = g[r], up = u[r];
                    float a = gate / (1.f + __expf(-gate)) * up;
                    act[(size_t)meta[lrow] * I_DIM + col] = (bf16)a;
                }
            }
        }
    }
}

// ---------------- GEMM2: act @ W_down^T (nibble-packed), atomic accumulate ----------------
__global__ __launch_bounds__(256) void gemm2_kernel(
    const bf16*     __restrict__ act,
    const unsigned* __restrict__ qpk,   // [E][H][I/8]
    const float*    __restrict__ sc,    // [E][H][11]
    const int*      __restrict__ counts,
    const int*      __restrict__ lists,
    const float*    __restrict__ wlists,
    float*          __restrict__ out)   // [T][H], pre-zeroed
{
    const int e   = blockIdx.z;
    const int cnt = counts[e];
    const int m0  = blockIdx.y * 128;
    if (m0 >= cnt) return;
    const int n0 = blockIdx.x * 128;

    __shared__ __align__(16) bf16 Al[128 * 64];
    __shared__ __align__(16) bf16 Bl[128 * 64];
    __shared__ int   meta[128];
    __shared__ float wmeta[128];

    const int tid = threadIdx.x;
    if (tid < 128) {
        int m = m0 + tid;
        int mm = (m < cnt) ? m : 0;
        meta[tid]  = lists[e * T_TOKENS + mm];
        wmeta[tid] = wlists[e * T_TOKENS + mm];
    }
    __syncthreads();

    const int lane = tid & 63;
    const int wv = tid >> 6;
    const int wm = wv >> 1, wn = wv & 1;

    floatx4 acc[4][4];
    #pragma unroll
    for (int i = 0; i < 4; ++i)
        #pragma unroll
        for (int j = 0; j < 4; ++j)
            acc[i][j] = (floatx4){0.f, 0.f, 0.f, 0.f};

    const int kg = tid & 7;
    const int rb = tid >> 3;

    for (int k0 = 0; k0 < I_DIM; k0 += 64) {
        #pragma unroll
        for (int j = 0; j < 4; ++j) {
            int g = tid + 256 * j;
            int row = g >> 3, cg = g & 7;
            bf16x8 v = *reinterpret_cast<const bf16x8*>(act + (size_t)meta[row] * I_DIM + k0 + cg * 8);
            *reinterpret_cast<bf16x8*>(&Al[g * 8]) = v;
        }
        #pragma unroll
        for (int j = 0; j < 4; ++j) {
            int r = rb + 32 * j;
            int grow = n0 + r;
            size_t rbase = (size_t)(e * H_DIM + grow);
            unsigned pd = qpk[rbase * 176 + (k0 >> 3) + kg];
            float s = sc[rbase * 11 + (k0 >> 7)];
            float m8s = -8.f * s;
            bf16x8 bv;
            #pragma unroll
            for (int jj = 0; jj < 8; ++jj)
                bv[jj] = (bf16)fmaf((float)((pd >> (4 * jj)) & 15u), s, m8s);
            *reinterpret_cast<bf16x8*>(&Bl[r * 64 + kg * 8]) = bv;
        }
        __syncthreads();
        #pragma unroll
        for (int ks = 0; ks < 2; ++ks) {
            const int kofs = ks * 32 + (lane >> 4) * 8;
            bf16x8 af[4], bfr[4];
            #pragma unroll
            for (int mt = 0; mt < 4; ++mt)
                af[mt] = *reinterpret_cast<const bf16x8*>(&Al[(wm * 64 + mt * 16 + (lane & 15)) * 64 + kofs]);
            #pragma unroll
            for (int nt = 0; nt < 4; ++nt)
                bfr[nt] = *reinterpret_cast<const bf16x8*>(&Bl[(wn * 64 + nt * 16 + (lane & 15)) * 64 + kofs]);
            #pragma unroll
            for (int mt = 0; mt < 4; ++mt)
                #pragma unroll
                for (int nt = 0; nt < 4; ++nt)
                    acc[mt][nt] = __builtin_amdgcn_mfma_f32_16x16x32_bf16(af[mt], bfr[nt], acc[mt][nt], 0, 0, 0);
        }
        __syncthreads();
    }

    const int rbase = (lane >> 4) * 4;
    const int cn = lane & 15;
    #pragma unroll
    for (int mt = 0; mt < 4; ++mt) {
        #pragma unroll
        for (int nt = 0; nt < 4; ++nt) {
            floatx4 v = acc[mt][nt];
            int col = n0 + wn * 64 + nt * 16 + cn;
            #pragma unroll
            for (int r = 0; r < 4; ++r) {
                int lrow = wm * 64 + mt * 16 + rbase + r;
                if (m0 + lrow < cnt) {
                    int tok = meta[lrow] >> 1;
                    unsafeAtomicAdd(&out[(size_t)tok * H_DIM + col], wmeta[lrow] * v[r]);
                }
            }
        }
    }
}

extern "C" void kernel_launch(void* const* d_in, const int* in_sizes, int n_in,
                              void* d_out, int out_size, void* d_ws, size_t ws_size,
                              hipStream_t stream)
{
    const float* router_logits = (const float*)d_in[0];
    const float* x             = (const float*)d_in[1];
    const int*   gu_q          = (const int*)d_in[2];
    const float* gu_s          = (const float*)d_in[3];
    const int*   dn_q          = (const int*)d_in[4];
    const float* dn_s          = (const float*)d_in[5];
    float* out = (float*)d_out;

    char* ws = (char*)d_ws;
    int*      counts = (int*)(ws + OFF_COUNTS);
    int*      lists  = (int*)(ws + OFF_LISTS);
    float*    wlists = (float*)(ws + OFF_WLISTS);
    bf16*     xb     = (bf16*)(ws + OFF_XB);
    bf16*     act    = (bf16*)(ws + OFF_ACT);
    unsigned* gu_pk  = (unsigned*)(ws + OFF_GUPK);
    unsigned* dn_pk  = (unsigned*)(ws + OFF_DNPK);

    hipMemsetAsync(counts, 0, E_NUM * sizeof(int), stream);
    hipMemsetAsync(out, 0, (size_t)out_size * sizeof(float), stream);

    // pack weights to nibbles; convert x to bf16
    const int n2_gu = E_NUM * 2 * I_DIM * H_DIM / 16;   // 2,883,584
    const int n2_dn = E_NUM * H_DIM * I_DIM / 16;       // 1,441,792
    pack_nib_kernel<<<(n2_gu + 255) / 256, 256, 0, stream>>>(gu_q, (uint2*)gu_pk, n2_gu);
    pack_nib_kernel<<<(n2_dn + 255) / 256, 256, 0, stream>>>(dn_q, (uint2*)dn_pk, n2_dn);
    xconv_kernel<<<T_TOKENS * H_DIM / 8 / 256, 256, 0, stream>>>(x, xb);

    router_kernel<<<T_TOKENS / 256, 256, 0, stream>>>(router_logits, counts, lists, wlists);
    gemm1_kernel<<<dim3(22, 16, 8), 256, 0, stream>>>(xb, gu_pk, gu_s, counts, lists, act);
    gemm2_kernel<<<dim3(16, 16, 8), 256, 0, stream>>>(act, dn_pk, dn_s, counts, lists, wlists, out);
}

// Round 3
// 522.243 us; speedup vs baseline: 1.0889x; 1.0889x over previous
//
#include <hip/hip_runtime.h>
#include <hip/hip_bf16.h>

#define T_TOKENS 2048
#define H_DIM    2048
#define I_DIM    1408
#define E_NUM    8

typedef __bf16 bf16;
typedef __attribute__((ext_vector_type(8))) __bf16  bf16x8;
typedef __attribute__((ext_vector_type(4))) float   floatx4;

// ---------------- ws layout (bytes) ----------------
// gu_pk: [E][22 n-tiles][32 k-tiles][128 r][64 k] bf16, XOR-swizzled granules = 92.3 MB
// dn_pk: [E][16 n-tiles][22 k-tiles][128 r][64 k] bf16, swizzled              = 46.1 MB
// tmp overlaps gu_pk (gu_pk dead after gemm1; tmp written by gemm2).
static const size_t OFF_COUNTS = 0;
static const size_t OFF_LISTS  = 256;
static const size_t OFF_WLISTS = OFF_LISTS + (size_t)T_TOKENS * E_NUM * 4;       // 65792
static const size_t OFF_XB     = 131328;                                          // 8 MB
static const size_t OFF_ACT    = OFF_XB + (size_t)T_TOKENS * H_DIM * 2;           // 11.5 MB
static const size_t OFF_GUPK   = OFF_ACT + (size_t)2 * T_TOKENS * I_DIM * 2;
static const size_t OFF_DNPK   = OFF_GUPK + (size_t)E_NUM * 22 * 32 * 16384;
static const size_t OFF_TMP    = OFF_GUPK;   // 32 MB, overlapped
// end = OFF_DNPK + 46.1 MB ≈ 158.5 MB

// ---------------- pack gate_up: dequant + tile + gate/up interleave + swizzle ----------------
// block b = e*2816 + grow (global gate_up row); thread t = k-granule (8 values).
__global__ __launch_bounds__(256) void pack_gu_kernel(const int* __restrict__ q,
                                                      const float* __restrict__ sc,
                                                      bf16* __restrict__ out)
{
    const int b = blockIdx.x;
    const int t = threadIdx.x;
    const int e = b / 2816;
    const int grow = b - e * 2816;
    const int4* qp = reinterpret_cast<const int4*>(q + (size_t)b * H_DIM) + t * 2;
    int4 a = qp[0], c = qp[1];
    float s = sc[(size_t)b * 16 + (t >> 4)];
    float m8s = -8.f * s;
    bf16x8 bv;
    bv[0] = (bf16)fmaf((float)a.x, s, m8s);
    bv[1] = (bf16)fmaf((float)a.y, s, m8s);
    bv[2] = (bf16)fmaf((float)a.z, s, m8s);
    bv[3] = (bf16)fmaf((float)a.w, s, m8s);
    bv[4] = (bf16)fmaf((float)c.x, s, m8s);
    bv[5] = (bf16)fmaf((float)c.y, s, m8s);
    bv[6] = (bf16)fmaf((float)c.z, s, m8s);
    bv[7] = (bf16)fmaf((float)c.w, s, m8s);
    const int is_up = grow >= I_DIM;
    const int icol  = grow - (is_up ? I_DIM : 0);
    const int nt    = icol >> 6;
    const int r     = ((((icol >> 4) & 3) * 2 + is_up) * 16) + (icol & 15);
    size_t dst = ((((size_t)e * 22 + nt) * 32 + (t >> 3)) * 128 + r) * 8 + ((t & 7) ^ (r & 7));
    reinterpret_cast<bf16x8*>(out)[dst] = bv;
}

// ---------------- pack down: dequant + tile + swizzle ----------------
// block b = e*2048 + grow (H-row); thread t < 176 = k-granule over I=1408.
__global__ __launch_bounds__(256) void pack_dn_kernel(const int* __restrict__ q,
                                                      const float* __restrict__ sc,
                                                      bf16* __restrict__ out)
{
    const int b = blockIdx.x;
    const int t = threadIdx.x;
    if (t >= 176) return;
    const int e = b >> 11;
    const int grow = b & 2047;
    const int4* qp = reinterpret_cast<const int4*>(q + (size_t)b * I_DIM) + t * 2;
    int4 a = qp[0], c = qp[1];
    float s = sc[(size_t)b * 11 + (t >> 4)];
    float m8s = -8.f * s;
    bf16x8 bv;
    bv[0] = (bf16)fmaf((float)a.x, s, m8s);
    bv[1] = (bf16)fmaf((float)a.y, s, m8s);
    bv[2] = (bf16)fmaf((float)a.z, s, m8s);
    bv[3] = (bf16)fmaf((float)a.w, s, m8s);
    bv[4] = (bf16)fmaf((float)c.x, s, m8s);
    bv[5] = (bf16)fmaf((float)c.y, s, m8s);
    bv[6] = (bf16)fmaf((float)c.z, s, m8s);
    bv[7] = (bf16)fmaf((float)c.w, s, m8s);
    const int nt = grow >> 7;
    const int r  = grow & 127;
    size_t dst = ((((size_t)e * 16 + nt) * 22 + (t >> 3)) * 128 + r) * 8 + ((t & 7) ^ (r & 7));
    reinterpret_cast<bf16x8*>(out)[dst] = bv;
}

// ---------------- x f32 -> bf16 ----------------
__global__ void xconv_kernel(const float* __restrict__ x, bf16* __restrict__ xb)
{
    int i = blockIdx.x * blockDim.x + threadIdx.x;
    const float4* x4 = reinterpret_cast<const float4*>(x) + (size_t)i * 2;
    float4 v0 = x4[0], v1 = x4[1];
    bf16x8 bv;
    bv[0] = (bf16)v0.x; bv[1] = (bf16)v0.y; bv[2] = (bf16)v0.z; bv[3] = (bf16)v0.w;
    bv[4] = (bf16)v1.x; bv[5] = (bf16)v1.y; bv[6] = (bf16)v1.z; bv[7] = (bf16)v1.w;
    *reinterpret_cast<bf16x8*>(xb + (size_t)i * 8) = bv;
}

// ---------------- routing ----------------
__global__ void router_kernel(const float* __restrict__ logits,
                              int* __restrict__ counts,
                              int* __restrict__ lists,
                              float* __restrict__ wlists)
{
    int t = blockIdx.x * blockDim.x + threadIdx.x;
    if (t >= T_TOKENS) return;
    const float* l = logits + (size_t)t * E_NUM;
    float v0 = -1e30f, v1 = -1e30f;
    int i0 = 0, i1 = 0;
    #pragma unroll
    for (int e = 0; e < E_NUM; ++e) {
        float v = l[e];
        if (v > v0) { v1 = v0; i1 = i0; v0 = v; i0 = e; }
        else if (v > v1) { v1 = v; i1 = e; }
    }
    float w0 = 1.f / (1.f + __expf(v1 - v0));
    float w1 = 1.f - w0;
    int p0 = atomicAdd(&counts[i0], 1);
    lists[i0 * T_TOKENS + p0] = t * 2 + 0;
    wlists[i0 * T_TOKENS + p0] = w0;
    int p1 = atomicAdd(&counts[i1], 1);
    lists[i1 * T_TOKENS + p1] = t * 2 + 1;
    wlists[i1 * T_TOKENS + p1] = w1;
}

// ---------------- GEMM1: xb @ W_gate_up^T (pre-dequant bf16, swizzled), fused SwiGLU ----------------
__global__ __launch_bounds__(256) void gemm1_kernel(
    const bf16* __restrict__ xb,
    const bf16* __restrict__ wpk,
    const int*  __restrict__ counts,
    const int*  __restrict__ lists,
    bf16*       __restrict__ act)
{
    const int e   = blockIdx.z;
    const int cnt = counts[e];
    const int m0  = blockIdx.y * 128;
    if (m0 >= cnt) return;
    const int nt  = blockIdx.x;     // 64 I-cols per tile (128 interleaved gate/up rows)

    __shared__ __align__(16) bf16 Al[8192];
    __shared__ __align__(16) bf16 Bl[8192];
    __shared__ int meta[128];

    const int tid = threadIdx.x;
    if (tid < 128) {
        int m = m0 + tid;
        meta[tid] = lists[e * T_TOKENS + (m < cnt ? m : 0)];
    }
    __syncthreads();

    const int lane = tid & 63;
    const int wv = tid >> 6;
    const int wm = wv >> 1, wn = wv & 1;

    // A staging addresses (constant across k-loop except global k advance)
    int    aoff[4];
    size_t agbl[4];
    #pragma unroll
    for (int j = 0; j < 4; ++j) {
        int g = tid + 256 * j;
        int arow = g >> 3, cg = g & 7;
        aoff[j] = arow * 64 + ((cg ^ (arow & 7)) * 8);
        agbl[j] = (size_t)(meta[arow] >> 1) * H_DIM + cg * 8;
    }
    const bf16* bt = wpk + ((size_t)e * 22 + nt) * (32 * 8192) + tid * 8;

    // fragment read offsets (constant)
    int afr[2][4], bfr[2][4];
    #pragma unroll
    for (int ks = 0; ks < 2; ++ks) {
        int gidx = ks * 4 + (lane >> 4);
        #pragma unroll
        for (int t4 = 0; t4 < 4; ++t4) {
            int ra = wm * 64 + t4 * 16 + (lane & 15);
            afr[ks][t4] = ra * 64 + ((gidx ^ (ra & 7)) * 8);
            int rb = wn * 64 + t4 * 16 + (lane & 15);
            bfr[ks][t4] = rb * 64 + ((gidx ^ (rb & 7)) * 8);
        }
    }

    floatx4 acc[4][4];
    #pragma unroll
    for (int i = 0; i < 4; ++i)
        #pragma unroll
        for (int j = 0; j < 4; ++j)
            acc[i][j] = (floatx4){0.f, 0.f, 0.f, 0.f};

    for (int k0 = 0; k0 < H_DIM; k0 += 64) {
        #pragma unroll
        for (int j = 0; j < 4; ++j) {
            bf16x8 v = *reinterpret_cast<const bf16x8*>(xb + agbl[j] + k0);
            *reinterpret_cast<bf16x8*>(&Al[aoff[j]]) = v;
        }
        const bf16* bsrc = bt + (size_t)(k0 >> 6) * 8192;
        #pragma unroll
        for (int j = 0; j < 4; ++j) {
            bf16x8 v = *reinterpret_cast<const bf16x8*>(bsrc + j * 2048);
            *reinterpret_cast<bf16x8*>(&Bl[tid * 8 + j * 2048]) = v;
        }
        __syncthreads();
        #pragma unroll
        for (int ks = 0; ks < 2; ++ks) {
            bf16x8 af[4], bff[4];
            #pragma unroll
            for (int mt = 0; mt < 4; ++mt)
                af[mt] = *reinterpret_cast<const bf16x8*>(&Al[afr[ks][mt]]);
            #pragma unroll
            for (int ntf = 0; ntf < 4; ++ntf)
                bff[ntf] = *reinterpret_cast<const bf16x8*>(&Bl[bfr[ks][ntf]]);
            #pragma unroll
            for (int mt = 0; mt < 4; ++mt)
                #pragma unroll
                for (int ntf = 0; ntf < 4; ++ntf)
                    acc[mt][ntf] = __builtin_amdgcn_mfma_f32_16x16x32_bf16(af[mt], bff[ntf], acc[mt][ntf], 0, 0, 0);
        }
        __syncthreads();
    }

    // epilogue: SwiGLU (gate = even B-row-tile, up = odd), scatter to act
    const int rbase = (lane >> 4) * 4;
    const int cn = lane & 15;
    #pragma unroll
    for (int mt = 0; mt < 4; ++mt) {
        #pragma unroll
        for (int j = 0; j < 2; ++j) {
            floatx4 g = acc[mt][2 * j];
            floatx4 u = acc[mt][2 * j + 1];
            int col = nt * 64 + (wn * 2 + j) * 16 + cn;
            #pragma unroll
            for (int r = 0; r < 4; ++r) {
                int lrow = wm * 64 + mt * 16 + rbase + r;
                if (m0 + lrow < cnt) {
                    float gate = g[r], up = u[r];
                    float a = gate / (1.f + __expf(-gate)) * up;
                    act[(size_t)meta[lrow] * I_DIM + col] = (bf16)a;
                }
            }
        }
    }
}

// ---------------- GEMM2: act @ W_down^T (pre-dequant bf16, swizzled), coalesced tmp ----------------
__global__ __launch_bounds__(256) void gemm2_kernel(
    const bf16*  __restrict__ act,
    const bf16*  __restrict__ wpk,
    const int*   __restrict__ counts,
    const int*   __restrict__ lists,
    const float* __restrict__ wlists,
    float*       __restrict__ tmp)
{
    const int e   = blockIdx.z;
    const int cnt = counts[e];
    const int m0  = blockIdx.y * 128;
    if (m0 >= cnt) return;
    const int nt  = blockIdx.x;     // 128 H-cols per tile

    __shared__ __align__(16) bf16 Al[8192];
    __shared__ __align__(16) bf16 Bl[8192];
    __shared__ int   meta[128];
    __shared__ float wmeta[128];

    const int tid = threadIdx.x;
    if (tid < 128) {
        int m = m0 + tid;
        int mm = (m < cnt) ? m : 0;
        meta[tid]  = lists[e * T_TOKENS + mm];
        wmeta[tid] = wlists[e * T_TOKENS + mm];
    }
    __syncthreads();

    const int lane = tid & 63;
    const int wv = tid >> 6;
    const int wm = wv >> 1, wn = wv & 1;

    int    aoff[4];
    size_t agbl[4];
    #pragma unroll
    for (int j = 0; j < 4; ++j) {
        int g = tid + 256 * j;
        int arow = g >> 3, cg = g & 7;
        aoff[j] = arow * 64 + ((cg ^ (arow & 7)) * 8);
        agbl[j] = (size_t)meta[arow] * I_DIM + cg * 8;
    }
    const bf16* bt = wpk + ((size_t)e * 16 + nt) * (22 * 8192) + tid * 8;

    int afr[2][4], bfr[2][4];
    #pragma unroll
    for (int ks = 0; ks < 2; ++ks) {
        int gidx = ks * 4 + (lane >> 4);
        #pragma unroll
        for (int t4 = 0; t4 < 4; ++t4) {
            int ra = wm * 64 + t4 * 16 + (lane & 15);
            afr[ks][t4] = ra * 64 + ((gidx ^ (ra & 7)) * 8);
            int rb = wn * 64 + t4 * 16 + (lane & 15);
            bfr[ks][t4] = rb * 64 + ((gidx ^ (rb & 7)) * 8);
        }
    }

    floatx4 acc[4][4];
    #pragma unroll
    for (int i = 0; i < 4; ++i)
        #pragma unroll
        for (int j = 0; j < 4; ++j)
            acc[i][j] = (floatx4){0.f, 0.f, 0.f, 0.f};

    for (int kt = 0; kt < 22; ++kt) {
        #pragma unroll
        for (int j = 0; j < 4; ++j) {
            bf16x8 v = *reinterpret_cast<const bf16x8*>(act + agbl[j] + kt * 64);
            *reinterpret_cast<bf16x8*>(&Al[aoff[j]]) = v;
        }
        const bf16* bsrc = bt + (size_t)kt * 8192;
        #pragma unroll
        for (int j = 0; j < 4; ++j) {
            bf16x8 v = *reinterpret_cast<const bf16x8*>(bsrc + j * 2048);
            *reinterpret_cast<bf16x8*>(&Bl[tid * 8 + j * 2048]) = v;
        }
        __syncthreads();
        #pragma unroll
        for (int ks = 0; ks < 2; ++ks) {
            bf16x8 af[4], bff[4];
            #pragma unroll
            for (int mt = 0; mt < 4; ++mt)
                af[mt] = *reinterpret_cast<const bf16x8*>(&Al[afr[ks][mt]]);
            #pragma unroll
            for (int ntf = 0; ntf < 4; ++ntf)
                bff[ntf] = *reinterpret_cast<const bf16x8*>(&Bl[bfr[ks][ntf]]);
            #pragma unroll
            for (int mt = 0; mt < 4; ++mt)
                #pragma unroll
                for (int ntf = 0; ntf < 4; ++ntf)
                    acc[mt][ntf] = __builtin_amdgcn_mfma_f32_16x16x32_bf16(af[mt], bff[ntf], acc[mt][ntf], 0, 0, 0);
        }
        __syncthreads();
    }

    const int rbase = (lane >> 4) * 4;
    const int cn = lane & 15;
    #pragma unroll
    for (int mt = 0; mt < 4; ++mt) {
        #pragma unroll
        for (int ntf = 0; ntf < 4; ++ntf) {
            floatx4 v = acc[mt][ntf];
            int col = nt * 128 + wn * 64 + ntf * 16 + cn;
            #pragma unroll
            for (int r = 0; r < 4; ++r) {
                int lrow = wm * 64 + mt * 16 + rbase + r;
                if (m0 + lrow < cnt) {
                    tmp[(size_t)meta[lrow] * H_DIM + col] = wmeta[lrow] * v[r];
                }
            }
        }
    }
}

// ---------------- finalize: out[t] = tmp[2t] + tmp[2t+1] ----------------
__global__ void finalize_kernel(const float* __restrict__ tmp, float* __restrict__ out)
{
    int i4 = blockIdx.x * blockDim.x + threadIdx.x;
    int t  = i4 >> 9;
    int h  = (i4 & 511) * 4;
    float4 a = *reinterpret_cast<const float4*>(tmp + ((size_t)2 * t) * H_DIM + h);
    float4 b = *reinterpret_cast<const float4*>(tmp + ((size_t)(2 * t + 1)) * H_DIM + h);
    float4 o;
    o.x = a.x + b.x; o.y = a.y + b.y; o.z = a.z + b.z; o.w = a.w + b.w;
    *reinterpret_cast<float4*>(out + (size_t)t * H_DIM + h) = o;
}

extern "C" void kernel_launch(void* const* d_in, const int* in_sizes, int n_in,
                              void* d_out, int out_size, void* d_ws, size_t ws_size,
                              hipStream_t stream)
{
    const float* router_logits = (const float*)d_in[0];
    const float* x             = (const float*)d_in[1];
    const int*   gu_q          = (const int*)d_in[2];
    const float* gu_s          = (const float*)d_in[3];
    const int*   dn_q          = (const int*)d_in[4];
    const float* dn_s          = (const float*)d_in[5];
    float* out = (float*)d_out;

    char* ws = (char*)d_ws;
    int*   counts = (int*)(ws + OFF_COUNTS);
    int*   lists  = (int*)(ws + OFF_LISTS);
    float* wlists = (float*)(ws + OFF_WLISTS);
    bf16*  xb     = (bf16*)(ws + OFF_XB);
    bf16*  act    = (bf16*)(ws + OFF_ACT);
    bf16*  gu_pk  = (bf16*)(ws + OFF_GUPK);
    bf16*  dn_pk  = (bf16*)(ws + OFF_DNPK);
    float* tmp    = (float*)(ws + OFF_TMP);   // overlaps gu_pk (dead after gemm1)

    hipMemsetAsync(counts, 0, E_NUM * sizeof(int), stream);

    pack_gu_kernel<<<E_NUM * 2816, 256, 0, stream>>>(gu_q, gu_s, gu_pk);
    pack_dn_kernel<<<E_NUM * 2048, 256, 0, stream>>>(dn_q, dn_s, dn_pk);
    xconv_kernel<<<T_TOKENS * H_DIM / 8 / 256, 256, 0, stream>>>(x, xb);
    router_kernel<<<T_TOKENS / 256, 256, 0, stream>>>(router_logits, counts, lists, wlists);

    gemm1_kernel<<<dim3(22, 16, 8), 256, 0, stream>>>(xb, gu_pk, counts, lists, act);
    gemm2_kernel<<<dim3(16, 16, 8), 256, 0, stream>>>(act, dn_pk, counts, lists, wlists, tmp);
    finalize_kernel<<<4096, 256, 0, stream>>>(tmp, out);
}